// Round 3
// baseline (344.875 us; speedup 1.0000x reference)
//
#include <hip/hip_runtime.h>

#define S_LEN  512
#define D_DIM  64
#define NH     16
#define R_LEN  1023
#define BHD    16384          // BH * D (elements)
#define PPITCH 68             // P tile pitch (ushort)

typedef __attribute__((ext_vector_type(8))) short   short8_t;
typedef __attribute__((ext_vector_type(8))) __bf16  bf16x8;
typedef __attribute__((ext_vector_type(4))) float   floatx4;

__device__ __forceinline__ unsigned short f2bf(float f) {
  union { float f; unsigned u; } v; v.f = f;
  return (unsigned short)((v.u + 0x7fffu + ((v.u >> 16) & 1u)) >> 16);  // RNE
}

__device__ __forceinline__ short8_t pack8s(float4 a, float4 b) {
  union { ushort4 u4[2]; short8_t s8; } u;
  u.u4[0] = (ushort4){ f2bf(a.x), f2bf(a.y), f2bf(a.z), f2bf(a.w) };
  u.u4[1] = (ushort4){ f2bf(b.x), f2bf(b.y), f2bf(b.z), f2bf(b.w) };
  return u.s8;
}
__device__ __forceinline__ bf16x8 pack8(float4 a, float4 b) {
  short8_t s = pack8s(a, b);
  return __builtin_bit_cast(bf16x8, s);
}
__device__ __forceinline__ bf16x8 ldfrag(const unsigned short* p) {   // 16B aligned
  short8_t s = *(const short8_t*)p;
  return __builtin_bit_cast(bf16x8, s);
}
__device__ __forceinline__ bf16x8 ldfrag8(const unsigned short* p) {  // 8B aligned
  union { ushort4 u4[2]; short8_t s8; } u;
  u.u4[0] = *(const ushort4*)p;
  u.u4[1] = *(const ushort4*)(p + 4);
  return __builtin_bit_cast(bf16x8, u.s8);
}
// swizzled 8-elem segment read: row r, segment seg (16B), pitch 64, seg ^= r&7
__device__ __forceinline__ bf16x8 ldseg(const unsigned short* buf, int r, int seg) {
  return ldfrag(buf + r * 64 + ((seg ^ (r & 7)) << 3));
}
// async global->LDS, 16B per lane, LDS dest = base + lane*16
__device__ __forceinline__ void async16(const void* g, void* l) {
  __builtin_amdgcn_global_load_lds(
      (const __attribute__((address_space(1))) unsigned int*)(unsigned long long)(uintptr_t)g,
      (__attribute__((address_space(3))) unsigned int*)(unsigned int)(uintptr_t)l,
      16, 0, 0);
}

// ---------------- pre-pass: fp32 -> bf16 convert (K, emb) ----------------
extern "C" __global__ void cvt_bf16(const float* __restrict__ src,
                                    unsigned short* __restrict__ dst, int n8) {
  int i = blockIdx.x * blockDim.x + threadIdx.x;
  if (i < n8) {
    const float* s = src + (size_t)i * 8;
    float4 a = *(const float4*)s, b = *(const float4*)(s + 4);
    *(short8_t*)(dst + (size_t)i * 8) = pack8s(a, b);
  }
}

// ---------------- pre-pass: V [s][bh][d] fp32 -> vtb [bh][d][s] bf16 ----------------
extern "C" __global__ void vtrans(const float* __restrict__ v,
                                  unsigned short* __restrict__ vtb) {
  __shared__ unsigned short t[64 * PPITCH];
  const int tid = threadIdx.x;
  const int bh  = blockIdx.x >> 3;
  const int j0  = (blockIdx.x & 7) << 6;
  for (int idx = tid; idx < 1024; idx += 256) {
    int jl = idx >> 4, cg = (idx & 15) << 2;
    float4 a = *(const float4*)(v + (size_t)(j0 + jl) * BHD + bh * D_DIM + cg);
    *(ushort4*)(t + jl * PPITCH + cg) = (ushort4){ f2bf(a.x), f2bf(a.y), f2bf(a.z), f2bf(a.w) };
  }
  __syncthreads();
  for (int slot = tid; slot < 512; slot += 256) {
    int d = slot >> 3, jseg = slot & 7;
    union { unsigned short u[8]; short8_t s8; } r;
    #pragma unroll
    for (int jj = 0; jj < 8; ++jj) r.u[jj] = t[(jseg * 8 + jj) * PPITCH + d];
    *(short8_t*)(vtb + ((size_t)bh * D_DIM + d) * S_LEN + j0 + jseg * 8) = r.s8;
  }
}

// ---------------- main attention kernel ----------------
extern "C" __global__ __launch_bounds__(256, 5)
void attn_relbias(const float* __restrict__ q, const unsigned short* __restrict__ kb,
                  const unsigned short* __restrict__ vtb,
                  const unsigned short* __restrict__ eb,
                  float* __restrict__ out)
{
  __shared__ unsigned short kjs[64 * 64];        // K_j tile, swizzled pitch-64
  __shared__ unsigned short vts[64 * 64];        // V^T tile, swizzled pitch-64
  __shared__ unsigned short ps [4][16 * PPITCH]; // per-wave P strip

  const int tid  = threadIdx.x;
  const int bh   = blockIdx.x >> 3;
  const int i0   = (blockIdx.x & 7) << 6;
  const int h    = bh & (NH - 1);
  const int wv   = tid >> 6;
  const int lane = tid & 63;
  const int l15  = lane & 15;
  const int quad = lane >> 4;
  const int iloc0 = wv * 16 + quad * 4;
  const int elo   = 3 - wv;            // wave's first bias e-block
  const int arow  = wv * 16 + l15;
  const int acol  = quad * 8;

  // ---- Q and K_i fragments straight from global (once per block) ----
  bf16x8 qa0, qa1, ia0, ia1;
  {
    const float* gq = q + (size_t)(i0 + arow) * BHD + bh * D_DIM + acol;
    qa0 = pack8(*(const float4*)gq,        *(const float4*)(gq + 4));
    qa1 = pack8(*(const float4*)(gq + 32), *(const float4*)(gq + 36));
    const unsigned short* gi = kb + (size_t)(i0 + arow) * BHD + bh * D_DIM + acol;
    ia0 = ldfrag(gi);
    ia1 = ldfrag(gi + 32);
  }

  floatx4 oacc[4];
  #pragma unroll
  for (int c = 0; c < 4; ++c) oacc[c] = (floatx4){0.f, 0.f, 0.f, 0.f};
  float m_i[4] = { -1e30f, -1e30f, -1e30f, -1e30f };
  float l_i[4] = { 0.f, 0.f, 0.f, 0.f };

  const int srow = (lane >> 3);            // staging: row within 8-row group
  const int sseg = (lane & 7) ^ (srow & 7);// swizzled source segment

  for (int j0 = 0; j0 < S_LEN; j0 += 64) {
    __syncthreads();   // B1: prior iteration's LDS reads done

    // ---- async stage K_j and V^T (swizzled, 16B/lane) ----
    {
      const unsigned short* kbj = kb + (size_t)j0 * BHD + bh * D_DIM;
      const unsigned short* vbj = vtb + (size_t)bh * (D_DIM * S_LEN) + j0;
      #pragma unroll
      for (int n = 0; n < 2; ++n) {
        int row = wv * 16 + n * 8 + srow;
        async16(kbj + (size_t)row * BHD + sseg * 8, &kjs[(wv * 16 + n * 8) * 64]);
        async16(vbj + (size_t)row * S_LEN + sseg * 8, &vts[(wv * 16 + n * 8) * 64]);
      }
    }

    // ---- bias MFMAs (regs + L2-resident bf16 emb; overlaps async staging) ----
    floatx4 bacc[5];
    {
      const int rbase = j0 - i0 + 448;
      #pragma unroll
      for (int ei = 0; ei < 5; ++ei) {
        int rg = rbase + (elo + ei) * 16 + l15;
        rg = min(rg, R_LEN - 1);                    // clamp touches only unused lanes
        const unsigned short* ep = eb + ((size_t)h * R_LEN + rg) * D_DIM + acol;
        floatx4 bz = (floatx4){0.f, 0.f, 0.f, 0.f};
        bz = __builtin_amdgcn_mfma_f32_16x16x32_bf16(ia0, ldfrag(ep),      bz, 0, 0, 0);
        bz = __builtin_amdgcn_mfma_f32_16x16x32_bf16(ia1, ldfrag(ep + 32), bz, 0, 0, 0);
        bacc[ei] = bz;
      }
    }
    __syncthreads();   // B2: staging visible (drains vmcnt)

    // ---- QK^T ----
    floatx4 qk[4];
    #pragma unroll
    for (int c = 0; c < 4; ++c) {
      bf16x8 kb0 = ldseg(kjs, c * 16 + l15, quad);
      bf16x8 kb1 = ldseg(kjs, c * 16 + l15, quad + 4);
      floatx4 acc = (floatx4){0.f, 0.f, 0.f, 0.f};
      acc = __builtin_amdgcn_mfma_f32_16x16x32_bf16(qa0, kb0, acc, 0, 0, 0);
      acc = __builtin_amdgcn_mfma_f32_16x16x32_bf16(qa1, kb1, acc, 0, 0, 0);
      qk[c] = acc;
    }

    // ---- add bias via skew-shuffle ----
    float sc[4][4];
    #pragma unroll
    for (int r = 0; r < 4; ++r) {
      const int o  = 15 - 4 * quad - r;
      const int ls = (lane & 48) + ((l15 + o) & 15);
      const bool hi = (l15 + o) >= 16;
      #pragma unroll
      for (int c = 0; c < 4; ++c) {
        float blo = __shfl(bacc[c][r],     ls);
        float bhi = __shfl(bacc[c + 1][r], ls);
        sc[c][r] = (qk[c][r] + (hi ? bhi : blo)) * 0.125f;
      }
    }

    // ---- online softmax ----
    float p[4][4];
    #pragma unroll
    for (int r = 0; r < 4; ++r) {
      float mx = fmaxf(fmaxf(sc[0][r], sc[1][r]), fmaxf(sc[2][r], sc[3][r]));
      #pragma unroll
      for (int off = 1; off < 16; off <<= 1) mx = fmaxf(mx, __shfl_xor(mx, off));
      float mnew  = fmaxf(m_i[r], mx);
      float alpha = __expf(m_i[r] - mnew);
      float rs = 0.f;
      #pragma unroll
      for (int c = 0; c < 4; ++c) { p[c][r] = __expf(sc[c][r] - mnew); rs += p[c][r]; }
      #pragma unroll
      for (int off = 1; off < 16; off <<= 1) rs += __shfl_xor(rs, off);
      l_i[r] = l_i[r] * alpha + rs;
      m_i[r] = mnew;
      #pragma unroll
      for (int c = 0; c < 4; ++c) oacc[c][r] *= alpha;
    }

    // ---- P round-trip through wave-private LDS ----
    unsigned short* psw = ps[wv];
    #pragma unroll
    for (int c = 0; c < 4; ++c) {
      #pragma unroll
      for (int r = 0; r < 4; ++r)
        psw[(quad * 4 + r) * PPITCH + c * 16 + l15] = f2bf(p[c][r]);
    }
    bf16x8 pa0 = ldfrag8(psw + l15 * PPITCH + acol);
    bf16x8 pa1 = ldfrag8(psw + l15 * PPITCH + acol + 32);
    #pragma unroll
    for (int c = 0; c < 4; ++c) {
      bf16x8 vb0 = ldseg(vts, c * 16 + l15, quad);
      bf16x8 vb1 = ldseg(vts, c * 16 + l15, quad + 4);
      oacc[c] = __builtin_amdgcn_mfma_f32_16x16x32_bf16(pa0, vb0, oacc[c], 0, 0, 0);
      oacc[c] = __builtin_amdgcn_mfma_f32_16x16x32_bf16(pa1, vb1, oacc[c], 0, 0, 0);
    }
  }

  // ---- epilogue ----
  #pragma unroll
  for (int r = 0; r < 4; ++r) {
    float inv = 1.f / l_i[r];
    int row = i0 + iloc0 + r;
    #pragma unroll
    for (int c = 0; c < 4; ++c)
      out[(size_t)row * BHD + bh * D_DIM + c * 16 + l15] = oacc[c][r] * inv;
  }
}

// ---------------- fallback (R2 kernel, used if ws too small) ----------------
#define PITCH 72
extern "C" __global__ __launch_bounds__(256, 4)
void attn_fb(const float* __restrict__ q, const float* __restrict__ k,
             const float* __restrict__ v, const float* __restrict__ emb,
             float* __restrict__ out)
{
  __shared__ unsigned short kjs[64 * PITCH];
  __shared__ unsigned short vts[64 * PITCH];
  __shared__ unsigned short ps [4][16 * PPITCH];

  const int tid  = threadIdx.x;
  const int bh   = blockIdx.x >> 3;
  const int i0   = (blockIdx.x & 7) << 6;
  const int h    = bh & (NH - 1);
  const int wv   = tid >> 6;
  const int lane = tid & 63;
  const int l15  = lane & 15;
  const int quad = lane >> 4;
  const int iloc0 = wv * 16 + quad * 4;
  const int elo   = 3 - wv;

  {
    const float* gq = q + (size_t)i0 * BHD + bh * D_DIM;
    const float* gk = k + (size_t)i0 * BHD + bh * D_DIM;
    for (int idx = tid; idx < 1024; idx += 256) {
      int row = idx >> 4, cg = (idx & 15) << 2;
      float4 a = *(const float4*)(gq + row * BHD + cg);
      float4 b = *(const float4*)(gk + row * BHD + cg);
      *(ushort4*)(vts + row * PITCH + cg) = (ushort4){ f2bf(a.x), f2bf(a.y), f2bf(a.z), f2bf(a.w) };
      *(ushort4*)(kjs + row * PITCH + cg) = (ushort4){ f2bf(b.x), f2bf(b.y), f2bf(b.z), f2bf(b.w) };
    }
  }
  __syncthreads();

  const int arow = wv * 16 + l15;
  const int acol = quad * 8;
  bf16x8 qa0 = ldfrag(vts + arow * PITCH + acol);
  bf16x8 qa1 = ldfrag(vts + arow * PITCH + acol + 32);
  bf16x8 ia0 = ldfrag(kjs + arow * PITCH + acol);
  bf16x8 ia1 = ldfrag(kjs + arow * PITCH + acol + 32);

  floatx4 oacc[4];
  #pragma unroll
  for (int c = 0; c < 4; ++c) oacc[c] = (floatx4){0.f, 0.f, 0.f, 0.f};
  float m_i[4] = { -1e30f, -1e30f, -1e30f, -1e30f };
  float l_i[4] = { 0.f, 0.f, 0.f, 0.f };

  for (int j0 = 0; j0 < S_LEN; j0 += 64) {
    __syncthreads();
    {
      const float* gk = k + (size_t)j0 * BHD + bh * D_DIM;
      for (int idx = tid; idx < 1024; idx += 256) {
        int row = idx >> 4, cg = (idx & 15) << 2;
        float4 b = *(const float4*)(gk + row * BHD + cg);
        *(ushort4*)(kjs + row * PITCH + cg) = (ushort4){ f2bf(b.x), f2bf(b.y), f2bf(b.z), f2bf(b.w) };
      }
    }
    {
      const float* gv = v + (size_t)j0 * BHD + bh * D_DIM;
      for (int idx = tid; idx < 1024; idx += 256) {
        int dg = idx & 15, jl = idx >> 4;
        float4 b = *(const float4*)(gv + jl * BHD + dg * 4);
        int d0 = dg * 4;
        vts[(d0 + 0) * PITCH + jl] = f2bf(b.x);
        vts[(d0 + 1) * PITCH + jl] = f2bf(b.y);
        vts[(d0 + 2) * PITCH + jl] = f2bf(b.z);
        vts[(d0 + 3) * PITCH + jl] = f2bf(b.w);
      }
    }
    floatx4 bacc[5];
    {
      const int rbase = j0 - i0 + 448;
      #pragma unroll
      for (int ei = 0; ei < 5; ++ei) {
        int rg = rbase + (elo + ei) * 16 + l15;
        rg = min(rg, R_LEN - 1);
        const float* ep = emb + ((size_t)h * R_LEN + rg) * D_DIM + acol;
        float4 e0 = *(const float4*)(ep);
        float4 e1 = *(const float4*)(ep + 4);
        float4 e2 = *(const float4*)(ep + 32);
        float4 e3 = *(const float4*)(ep + 36);
        floatx4 bz = (floatx4){0.f, 0.f, 0.f, 0.f};
        bz = __builtin_amdgcn_mfma_f32_16x16x32_bf16(ia0, pack8(e0, e1), bz, 0, 0, 0);
        bz = __builtin_amdgcn_mfma_f32_16x16x32_bf16(ia1, pack8(e2, e3), bz, 0, 0, 0);
        bacc[ei] = bz;
      }
    }
    __syncthreads();

    floatx4 qk[4];
    #pragma unroll
    for (int c = 0; c < 4; ++c) {
      bf16x8 kb0 = ldfrag(kjs + (c * 16 + l15) * PITCH + acol);
      bf16x8 kb1 = ldfrag(kjs + (c * 16 + l15) * PITCH + acol + 32);
      floatx4 acc = (floatx4){0.f, 0.f, 0.f, 0.f};
      acc = __builtin_amdgcn_mfma_f32_16x16x32_bf16(qa0, kb0, acc, 0, 0, 0);
      acc = __builtin_amdgcn_mfma_f32_16x16x32_bf16(qa1, kb1, acc, 0, 0, 0);
      qk[c] = acc;
    }
    float sc[4][4];
    #pragma unroll
    for (int r = 0; r < 4; ++r) {
      const int o  = 15 - 4 * quad - r;
      const int ls = (lane & 48) + ((l15 + o) & 15);
      const bool hi = (l15 + o) >= 16;
      #pragma unroll
      for (int c = 0; c < 4; ++c) {
        float blo = __shfl(bacc[c][r],     ls);
        float bhi = __shfl(bacc[c + 1][r], ls);
        sc[c][r] = (qk[c][r] + (hi ? bhi : blo)) * 0.125f;
      }
    }
    float p[4][4];
    #pragma unroll
    for (int r = 0; r < 4; ++r) {
      float mx = fmaxf(fmaxf(sc[0][r], sc[1][r]), fmaxf(sc[2][r], sc[3][r]));
      #pragma unroll
      for (int off = 1; off < 16; off <<= 1) mx = fmaxf(mx, __shfl_xor(mx, off));
      float mnew  = fmaxf(m_i[r], mx);
      float alpha = __expf(m_i[r] - mnew);
      float rs = 0.f;
      #pragma unroll
      for (int c = 0; c < 4; ++c) { p[c][r] = __expf(sc[c][r] - mnew); rs += p[c][r]; }
      #pragma unroll
      for (int off = 1; off < 16; off <<= 1) rs += __shfl_xor(rs, off);
      l_i[r] = l_i[r] * alpha + rs;
      m_i[r] = mnew;
      #pragma unroll
      for (int c = 0; c < 4; ++c) oacc[c][r] *= alpha;
    }
    unsigned short* psw = ps[wv];
    #pragma unroll
    for (int c = 0; c < 4; ++c) {
      #pragma unroll
      for (int r = 0; r < 4; ++r)
        psw[(quad * 4 + r) * PPITCH + c * 16 + l15] = f2bf(p[c][r]);
    }
    bf16x8 pa0 = ldfrag8(psw + l15 * PPITCH + acol);
    bf16x8 pa1 = ldfrag8(psw + l15 * PPITCH + acol + 32);
    #pragma unroll
    for (int c = 0; c < 4; ++c) {
      bf16x8 vb0 = ldfrag(vts + (c * 16 + l15) * PITCH + acol);
      bf16x8 vb1 = ldfrag(vts + (c * 16 + l15) * PITCH + acol + 32);
      oacc[c] = __builtin_amdgcn_mfma_f32_16x16x32_bf16(pa0, vb0, oacc[c], 0, 0, 0);
      oacc[c] = __builtin_amdgcn_mfma_f32_16x16x32_bf16(pa1, vb1, oacc[c], 0, 0, 0);
    }
  }
  #pragma unroll
  for (int r = 0; r < 4; ++r) {
    float inv = 1.f / l_i[r];
    int row = i0 + iloc0 + r;
    #pragma unroll
    for (int c = 0; c < 4; ++c)
      out[(size_t)row * BHD + bh * D_DIM + c * 16 + l15] = oacc[c][r] * inv;
  }
}

extern "C" void kernel_launch(void* const* d_in, const int* in_sizes, int n_in,
                              void* d_out, int out_size, void* d_ws, size_t ws_size,
                              hipStream_t stream) {
  const float* q   = (const float*)d_in[0];
  const float* k   = (const float*)d_in[1];
  const float* v   = (const float*)d_in[2];
  const float* emb = (const float*)d_in[3];
  float* out = (float*)d_out;

  const size_t kb_off  = 0;                       // 512*256*64 bf16 = 16 MiB
  const size_t vtb_off = (size_t)512 * 256 * 64 * 2;
  const size_t eb_off  = vtb_off * 2;             // + 16 MiB
  const size_t need    = eb_off + (size_t)NH * R_LEN * D_DIM * 2;

  if (ws_size >= need) {
    unsigned short* kbp  = (unsigned short*)((char*)d_ws + kb_off);
    unsigned short* vtbp = (unsigned short*)((char*)d_ws + vtb_off);
    unsigned short* ebp  = (unsigned short*)((char*)d_ws + eb_off);
    // K: 512*256*64 = 8388608 elems -> 1048576 x8
    hipLaunchKernelGGL(cvt_bf16, dim3(4096), dim3(256), 0, stream, k, kbp, 1048576);
    // emb: 16*1023*64 = 1047552 elems -> 130944 x8
    hipLaunchKernelGGL(cvt_bf16, dim3(512), dim3(256), 0, stream, emb, ebp, 130944);
    hipLaunchKernelGGL(vtrans, dim3(2048), dim3(256), 0, stream, v, vtbp);
    hipLaunchKernelGGL(attn_relbias, dim3(2048), dim3(256), 0, stream,
                       q, kbp, vtbp, ebp, out);
  } else {
    hipLaunchKernelGGL(attn_fb, dim3(2048), dim3(256), 0, stream, q, k, v, emb, out);
  }
}

// Round 4
// 327.510 us; speedup vs baseline: 1.0530x; 1.0530x over previous
//
#include <hip/hip_runtime.h>

#define S_LEN  512
#define D_DIM  64
#define NH     16
#define R_LEN  1023
#define BHD    16384          // BH * D (elements)
#define PPITCH 68             // P tile pitch (ushort)

typedef __attribute__((ext_vector_type(8))) short   short8_t;
typedef __attribute__((ext_vector_type(8))) __bf16  bf16x8;
typedef __attribute__((ext_vector_type(4))) float   floatx4;

__device__ __forceinline__ unsigned short f2bf(float f) {
  union { float f; unsigned u; } v; v.f = f;
  return (unsigned short)((v.u + 0x7fffu + ((v.u >> 16) & 1u)) >> 16);  // RNE
}
__device__ __forceinline__ short8_t pack8s(float4 a, float4 b) {
  union { ushort4 u4[2]; short8_t s8; } u;
  u.u4[0] = (ushort4){ f2bf(a.x), f2bf(a.y), f2bf(a.z), f2bf(a.w) };
  u.u4[1] = (ushort4){ f2bf(b.x), f2bf(b.y), f2bf(b.z), f2bf(b.w) };
  return u.s8;
}
__device__ __forceinline__ bf16x8 pack8(float4 a, float4 b) {
  short8_t s = pack8s(a, b);
  return __builtin_bit_cast(bf16x8, s);
}
__device__ __forceinline__ bf16x8 ldfrag(const unsigned short* p) {   // 16B aligned
  short8_t s = *(const short8_t*)p;
  return __builtin_bit_cast(bf16x8, s);
}
__device__ __forceinline__ bf16x8 ldfrag8(const unsigned short* p) {  // 8B aligned
  union { ushort4 u4[2]; short8_t s8; } u;
  u.u4[0] = *(const ushort4*)p;
  u.u4[1] = *(const ushort4*)(p + 4);
  return __builtin_bit_cast(bf16x8, u.s8);
}

// ---------------- merged pre-pass: K->bf16, emb->bf16, V->V^T bf16 ----------------
extern "C" __global__ void prepass(const float* __restrict__ k, const float* __restrict__ v,
                                   const float* __restrict__ emb,
                                   unsigned short* __restrict__ kb,
                                   unsigned short* __restrict__ vtb,
                                   unsigned short* __restrict__ eb) {
  __shared__ unsigned short t[64 * PPITCH];
  const int bid = blockIdx.x;
  const int tid = threadIdx.x;
  if (bid < 4096) {                       // K: 8.39M elems, 8/thread
    size_t i = (size_t)bid * 256 + tid;
    const float* s = k + i * 8;
    float4 a = *(const float4*)s, b = *(const float4*)(s + 4);
    *(short8_t*)(kb + i * 8) = pack8s(a, b);
  } else if (bid < 4608) {                // emb: 1047552 elems = 130944 x8
    size_t i = (size_t)(bid - 4096) * 256 + tid;
    if (i < 130944) {
      const float* s = emb + i * 8;
      float4 a = *(const float4*)s, b = *(const float4*)(s + 4);
      *(short8_t*)(eb + i * 8) = pack8s(a, b);
    }
  } else {                                // V transpose: [s][bh][d] -> [bh][d][s]
    const int b2 = bid - 4608;
    const int bh = b2 >> 3;
    const int j0 = (b2 & 7) << 6;
    for (int idx = tid; idx < 1024; idx += 256) {
      int jl = idx >> 4, cg = (idx & 15) << 2;
      float4 a = *(const float4*)(v + (size_t)(j0 + jl) * BHD + bh * D_DIM + cg);
      *(ushort4*)(t + jl * PPITCH + cg) = (ushort4){ f2bf(a.x), f2bf(a.y), f2bf(a.z), f2bf(a.w) };
    }
    __syncthreads();
    for (int slot = tid; slot < 512; slot += 256) {
      int d = slot >> 3, jseg = slot & 7;
      union { unsigned short u[8]; short8_t s8; } r;
      #pragma unroll
      for (int jj = 0; jj < 8; ++jj) r.u[jj] = t[(jseg * 8 + jj) * PPITCH + d];
      *(short8_t*)(vtb + ((size_t)bh * D_DIM + d) * S_LEN + j0 + jseg * 8) = r.s8;
    }
  }
}

// ---------------- main attention kernel: barrier-free ----------------
extern "C" __global__ __launch_bounds__(256, 3)
void attn_relbias(const float* __restrict__ q, const unsigned short* __restrict__ kb,
                  const unsigned short* __restrict__ vtb,
                  const unsigned short* __restrict__ eb,
                  float* __restrict__ out)
{
  __shared__ unsigned short ps[4][16 * PPITCH];   // per-wave P strip (only LDS use)

  const int tid  = threadIdx.x;
  const int bh   = blockIdx.x >> 3;
  const int i0   = (blockIdx.x & 7) << 6;
  const int h    = bh & (NH - 1);
  const int wv   = tid >> 6;
  const int lane = tid & 63;
  const int l15  = lane & 15;
  const int quad = lane >> 4;
  const int iloc0 = wv * 16 + quad * 4;
  const int elo   = 3 - wv;            // wave's first bias e-block
  const int arow  = wv * 16 + l15;
  const int acol  = quad * 8;

  // ---- Q and K_i fragments straight from global (once per block) ----
  bf16x8 qa0, qa1, ia0, ia1;
  {
    const float* gq = q + (size_t)(i0 + arow) * BHD + bh * D_DIM + acol;
    qa0 = pack8(*(const float4*)gq,        *(const float4*)(gq + 4));
    qa1 = pack8(*(const float4*)(gq + 32), *(const float4*)(gq + 36));
    const unsigned short* gi = kb + (size_t)(i0 + arow) * BHD + bh * D_DIM + acol;
    ia0 = ldfrag(gi);
    ia1 = ldfrag(gi + 32);
  }

  const unsigned short* kbase = kb  + (size_t)bh * D_DIM + acol;     // + row*BHD
  const unsigned short* vbase = vtb + (size_t)bh * D_DIM * S_LEN;    // + d*512 + j
  const unsigned short* ebase = eb  + (size_t)h * R_LEN * D_DIM + acol;

  floatx4 oacc[4];
  #pragma unroll
  for (int c = 0; c < 4; ++c) oacc[c] = (floatx4){0.f, 0.f, 0.f, 0.f};
  float m_i[4] = { -1e30f, -1e30f, -1e30f, -1e30f };
  float l_i[4] = { 0.f, 0.f, 0.f, 0.f };

  for (int j0 = 0; j0 < S_LEN; j0 += 64) {
    // ---- issue emb + K fragment loads (consumed in this order) ----
    bf16x8 ef[10];
    {
      const int rbase = j0 - i0 + 448;
      #pragma unroll
      for (int ei = 0; ei < 5; ++ei) {
        int rg = rbase + (elo + ei) * 16 + l15;
        rg = min(rg, R_LEN - 1);                 // clamp touches only unused lanes
        const unsigned short* ep = ebase + (size_t)rg * D_DIM;
        ef[2 * ei]     = ldfrag(ep);
        ef[2 * ei + 1] = ldfrag(ep + 32);
      }
    }
    bf16x8 kf[8];
    #pragma unroll
    for (int c = 0; c < 4; ++c) {
      const unsigned short* kp = kbase + (size_t)(j0 + c * 16 + l15) * BHD;
      kf[2 * c]     = ldfrag(kp);
      kf[2 * c + 1] = ldfrag(kp + 32);
    }

    // ---- bias MFMAs ----
    floatx4 bacc[5];
    #pragma unroll
    for (int ei = 0; ei < 5; ++ei) {
      floatx4 bz = (floatx4){0.f, 0.f, 0.f, 0.f};
      bz = __builtin_amdgcn_mfma_f32_16x16x32_bf16(ia0, ef[2 * ei],     bz, 0, 0, 0);
      bz = __builtin_amdgcn_mfma_f32_16x16x32_bf16(ia1, ef[2 * ei + 1], bz, 0, 0, 0);
      bacc[ei] = bz;
    }

    // ---- QK^T ----
    floatx4 qk[4];
    #pragma unroll
    for (int c = 0; c < 4; ++c) {
      floatx4 acc = (floatx4){0.f, 0.f, 0.f, 0.f};
      acc = __builtin_amdgcn_mfma_f32_16x16x32_bf16(qa0, kf[2 * c],     acc, 0, 0, 0);
      acc = __builtin_amdgcn_mfma_f32_16x16x32_bf16(qa1, kf[2 * c + 1], acc, 0, 0, 0);
      qk[c] = acc;
    }

    // ---- issue V^T loads now; softmax below hides their latency ----
    bf16x8 vf[8];
    #pragma unroll
    for (int c = 0; c < 4; ++c) {
      const unsigned short* vp = vbase + (size_t)(c * 16 + l15) * S_LEN + j0 + acol;
      vf[2 * c]     = ldfrag(vp);
      vf[2 * c + 1] = ldfrag(vp + 32);
    }

    // ---- add bias via skew-shuffle ----
    float sc[4][4];
    #pragma unroll
    for (int r = 0; r < 4; ++r) {
      const int o  = 15 - 4 * quad - r;
      const int ls = (lane & 48) + ((l15 + o) & 15);
      const bool hi = (l15 + o) >= 16;
      #pragma unroll
      for (int c = 0; c < 4; ++c) {
        float blo = __shfl(bacc[c][r],     ls);
        float bhi = __shfl(bacc[c + 1][r], ls);
        sc[c][r] = (qk[c][r] + (hi ? bhi : blo)) * 0.125f;
      }
    }

    // ---- online softmax (rows live in 16-lane quads) ----
    float p[4][4];
    #pragma unroll
    for (int r = 0; r < 4; ++r) {
      float mx = fmaxf(fmaxf(sc[0][r], sc[1][r]), fmaxf(sc[2][r], sc[3][r]));
      #pragma unroll
      for (int off = 1; off < 16; off <<= 1) mx = fmaxf(mx, __shfl_xor(mx, off));
      float mnew  = fmaxf(m_i[r], mx);
      float alpha = __expf(m_i[r] - mnew);
      float rs = 0.f;
      #pragma unroll
      for (int c = 0; c < 4; ++c) { p[c][r] = __expf(sc[c][r] - mnew); rs += p[c][r]; }
      #pragma unroll
      for (int off = 1; off < 16; off <<= 1) rs += __shfl_xor(rs, off);
      l_i[r] = l_i[r] * alpha + rs;
      m_i[r] = mnew;
      #pragma unroll
      for (int c = 0; c < 4; ++c) oacc[c][r] *= alpha;
    }

    // ---- P round-trip through wave-private LDS (no barrier needed) ----
    unsigned short* psw = ps[wv];
    #pragma unroll
    for (int c = 0; c < 4; ++c) {
      #pragma unroll
      for (int r = 0; r < 4; ++r)
        psw[(quad * 4 + r) * PPITCH + c * 16 + l15] = f2bf(p[c][r]);
    }
    bf16x8 pa0 = ldfrag8(psw + l15 * PPITCH + acol);
    bf16x8 pa1 = ldfrag8(psw + l15 * PPITCH + acol + 32);

    // ---- PV ----
    #pragma unroll
    for (int c = 0; c < 4; ++c) {
      oacc[c] = __builtin_amdgcn_mfma_f32_16x16x32_bf16(pa0, vf[2 * c],     oacc[c], 0, 0, 0);
      oacc[c] = __builtin_amdgcn_mfma_f32_16x16x32_bf16(pa1, vf[2 * c + 1], oacc[c], 0, 0, 0);
    }
  }

  // ---- epilogue ----
  #pragma unroll
  for (int r = 0; r < 4; ++r) {
    float inv = 1.f / l_i[r];
    int row = i0 + iloc0 + r;
    #pragma unroll
    for (int c = 0; c < 4; ++c)
      out[(size_t)row * BHD + bh * D_DIM + c * 16 + l15] = oacc[c][r] * inv;
  }
}

// ---------------- fallback (used only if ws too small) ----------------
#define PITCH 72
extern "C" __global__ __launch_bounds__(256, 4)
void attn_fb(const float* __restrict__ q, const float* __restrict__ k,
             const float* __restrict__ v, const float* __restrict__ emb,
             float* __restrict__ out)
{
  __shared__ unsigned short kjs[64 * PITCH];
  __shared__ unsigned short vts[64 * PITCH];
  __shared__ unsigned short ps [4][16 * PPITCH];

  const int tid  = threadIdx.x;
  const int bh   = blockIdx.x >> 3;
  const int i0   = (blockIdx.x & 7) << 6;
  const int h    = bh & (NH - 1);
  const int wv   = tid >> 6;
  const int lane = tid & 63;
  const int l15  = lane & 15;
  const int quad = lane >> 4;
  const int iloc0 = wv * 16 + quad * 4;
  const int elo   = 3 - wv;

  {
    const float* gq = q + (size_t)i0 * BHD + bh * D_DIM;
    const float* gk = k + (size_t)i0 * BHD + bh * D_DIM;
    for (int idx = tid; idx < 1024; idx += 256) {
      int row = idx >> 4, cg = (idx & 15) << 2;
      float4 a = *(const float4*)(gq + row * BHD + cg);
      float4 b = *(const float4*)(gk + row * BHD + cg);
      *(ushort4*)(vts + row * PITCH + cg) = (ushort4){ f2bf(a.x), f2bf(a.y), f2bf(a.z), f2bf(a.w) };
      *(ushort4*)(kjs + row * PITCH + cg) = (ushort4){ f2bf(b.x), f2bf(b.y), f2bf(b.z), f2bf(b.w) };
    }
  }
  __syncthreads();

  const int arow = wv * 16 + l15;
  const int acol = quad * 8;
  bf16x8 qa0 = ldfrag(vts + arow * PITCH + acol);
  bf16x8 qa1 = ldfrag(vts + arow * PITCH + acol + 32);
  bf16x8 ia0 = ldfrag(kjs + arow * PITCH + acol);
  bf16x8 ia1 = ldfrag(kjs + arow * PITCH + acol + 32);

  floatx4 oacc[4];
  #pragma unroll
  for (int c = 0; c < 4; ++c) oacc[c] = (floatx4){0.f, 0.f, 0.f, 0.f};
  float m_i[4] = { -1e30f, -1e30f, -1e30f, -1e30f };
  float l_i[4] = { 0.f, 0.f, 0.f, 0.f };

  for (int j0 = 0; j0 < S_LEN; j0 += 64) {
    __syncthreads();
    {
      const float* gk = k + (size_t)j0 * BHD + bh * D_DIM;
      for (int idx = tid; idx < 1024; idx += 256) {
        int row = idx >> 4, cg = (idx & 15) << 2;
        float4 b = *(const float4*)(gk + row * BHD + cg);
        *(ushort4*)(kjs + row * PITCH + cg) = (ushort4){ f2bf(b.x), f2bf(b.y), f2bf(b.z), f2bf(b.w) };
      }
    }
    {
      const float* gv = v + (size_t)j0 * BHD + bh * D_DIM;
      for (int idx = tid; idx < 1024; idx += 256) {
        int dg = idx & 15, jl = idx >> 4;
        float4 b = *(const float4*)(gv + jl * BHD + dg * 4);
        int d0 = dg * 4;
        vts[(d0 + 0) * PITCH + jl] = f2bf(b.x);
        vts[(d0 + 1) * PITCH + jl] = f2bf(b.y);
        vts[(d0 + 2) * PITCH + jl] = f2bf(b.z);
        vts[(d0 + 3) * PITCH + jl] = f2bf(b.w);
      }
    }
    floatx4 bacc[5];
    {
      const int rbase = j0 - i0 + 448;
      #pragma unroll
      for (int ei = 0; ei < 5; ++ei) {
        int rg = rbase + (elo + ei) * 16 + l15;
        rg = min(rg, R_LEN - 1);
        const float* ep = emb + ((size_t)h * R_LEN + rg) * D_DIM + acol;
        float4 e0 = *(const float4*)(ep);
        float4 e1 = *(const float4*)(ep + 4);
        float4 e2 = *(const float4*)(ep + 32);
        float4 e3 = *(const float4*)(ep + 36);
        floatx4 bz = (floatx4){0.f, 0.f, 0.f, 0.f};
        bz = __builtin_amdgcn_mfma_f32_16x16x32_bf16(ia0, pack8(e0, e1), bz, 0, 0, 0);
        bz = __builtin_amdgcn_mfma_f32_16x16x32_bf16(ia1, pack8(e2, e3), bz, 0, 0, 0);
        bacc[ei] = bz;
      }
    }
    __syncthreads();

    floatx4 qk[4];
    #pragma unroll
    for (int c = 0; c < 4; ++c) {
      bf16x8 kb0 = ldfrag(kjs + (c * 16 + l15) * PITCH + acol);
      bf16x8 kb1 = ldfrag(kjs + (c * 16 + l15) * PITCH + acol + 32);
      floatx4 acc = (floatx4){0.f, 0.f, 0.f, 0.f};
      acc = __builtin_amdgcn_mfma_f32_16x16x32_bf16(qa0, kb0, acc, 0, 0, 0);
      acc = __builtin_amdgcn_mfma_f32_16x16x32_bf16(qa1, kb1, acc, 0, 0, 0);
      qk[c] = acc;
    }
    float sc[4][4];
    #pragma unroll
    for (int r = 0; r < 4; ++r) {
      const int o  = 15 - 4 * quad - r;
      const int ls = (lane & 48) + ((l15 + o) & 15);
      const bool hi = (l15 + o) >= 16;
      #pragma unroll
      for (int c = 0; c < 4; ++c) {
        float blo = __shfl(bacc[c][r],     ls);
        float bhi = __shfl(bacc[c + 1][r], ls);
        sc[c][r] = (qk[c][r] + (hi ? bhi : blo)) * 0.125f;
      }
    }
    float p[4][4];
    #pragma unroll
    for (int r = 0; r < 4; ++r) {
      float mx = fmaxf(fmaxf(sc[0][r], sc[1][r]), fmaxf(sc[2][r], sc[3][r]));
      #pragma unroll
      for (int off = 1; off < 16; off <<= 1) mx = fmaxf(mx, __shfl_xor(mx, off));
      float mnew  = fmaxf(m_i[r], mx);
      float alpha = __expf(m_i[r] - mnew);
      float rs = 0.f;
      #pragma unroll
      for (int c = 0; c < 4; ++c) { p[c][r] = __expf(sc[c][r] - mnew); rs += p[c][r]; }
      #pragma unroll
      for (int off = 1; off < 16; off <<= 1) rs += __shfl_xor(rs, off);
      l_i[r] = l_i[r] * alpha + rs;
      m_i[r] = mnew;
      #pragma unroll
      for (int c = 0; c < 4; ++c) oacc[c][r] *= alpha;
    }
    unsigned short* psw = ps[wv];
    #pragma unroll
    for (int c = 0; c < 4; ++c) {
      #pragma unroll
      for (int r = 0; r < 4; ++r)
        psw[(quad * 4 + r) * PPITCH + c * 16 + l15] = f2bf(p[c][r]);
    }
    bf16x8 pa0 = ldfrag8(psw + l15 * PPITCH + acol);
    bf16x8 pa1 = ldfrag8(psw + l15 * PPITCH + acol + 32);
    #pragma unroll
    for (int c = 0; c < 4; ++c) {
      bf16x8 vb0 = ldfrag(vts + (c * 16 + l15) * PITCH + acol);
      bf16x8 vb1 = ldfrag(vts + (c * 16 + l15) * PITCH + acol + 32);
      oacc[c] = __builtin_amdgcn_mfma_f32_16x16x32_bf16(pa0, vb0, oacc[c], 0, 0, 0);
      oacc[c] = __builtin_amdgcn_mfma_f32_16x16x32_bf16(pa1, vb1, oacc[c], 0, 0, 0);
    }
  }
  #pragma unroll
  for (int r = 0; r < 4; ++r) {
    float inv = 1.f / l_i[r];
    int row = i0 + iloc0 + r;
    #pragma unroll
    for (int c = 0; c < 4; ++c)
      out[(size_t)row * BHD + bh * D_DIM + c * 16 + l15] = oacc[c][r] * inv;
  }
}

extern "C" void kernel_launch(void* const* d_in, const int* in_sizes, int n_in,
                              void* d_out, int out_size, void* d_ws, size_t ws_size,
                              hipStream_t stream) {
  const float* q   = (const float*)d_in[0];
  const float* k   = (const float*)d_in[1];
  const float* v   = (const float*)d_in[2];
  const float* emb = (const float*)d_in[3];
  float* out = (float*)d_out;

  const size_t kb_off  = 0;                       // 16 MiB
  const size_t vtb_off = (size_t)512 * 256 * 64 * 2;
  const size_t eb_off  = vtb_off * 2;             // + 16 MiB
  const size_t need    = eb_off + (size_t)NH * R_LEN * D_DIM * 2;

  if (ws_size >= need) {
    unsigned short* kbp  = (unsigned short*)((char*)d_ws + kb_off);
    unsigned short* vtbp = (unsigned short*)((char*)d_ws + vtb_off);
    unsigned short* ebp  = (unsigned short*)((char*)d_ws + eb_off);
    hipLaunchKernelGGL(prepass, dim3(6656), dim3(256), 0, stream, k, v, emb, kbp, vtbp, ebp);
    hipLaunchKernelGGL(attn_relbias, dim3(2048), dim3(256), 0, stream,
                       q, kbp, vtbp, ebp, out);
  } else {
    hipLaunchKernelGGL(attn_fb, dim3(2048), dim3(256), 0, stream, q, k, v, emb, out);
  }
}

// Round 5
// 213.123 us; speedup vs baseline: 1.6182x; 1.5367x over previous
//
#include <hip/hip_runtime.h>
#include <hip/hip_bf16.h>

#define S_LEN  512
#define D_DIM  64
#define NH     16
#define R_LEN  1023
#define BHD    16384          // BH * D (elements)
#define PPITCH 68             // P tile pitch (ushort) - conflict-free writes

typedef __attribute__((ext_vector_type(8))) short   short8_t;
typedef __attribute__((ext_vector_type(8))) __bf16  bf16x8;
typedef __attribute__((ext_vector_type(4))) float   floatx4;

__device__ __forceinline__ unsigned short f2bf(float f) {
  union { float f; unsigned u; } v; v.f = f;
  return (unsigned short)((v.u + 0x7fffu + ((v.u >> 16) & 1u)) >> 16);  // RNE
}
__device__ __forceinline__ ushort2 c2(float x, float y) {
  __hip_bfloat162 h = __float22bfloat162_rn(float2{x, y});
  union { __hip_bfloat162 h; ushort2 u; } v; v.h = h; return v.u;
}
__device__ __forceinline__ short8_t pack8s(float4 a, float4 b) {
  union { ushort2 u2[4]; short8_t s8; } u;
  u.u2[0] = c2(a.x, a.y); u.u2[1] = c2(a.z, a.w);
  u.u2[2] = c2(b.x, b.y); u.u2[3] = c2(b.z, b.w);
  return u.s8;
}
__device__ __forceinline__ bf16x8 pack8(float4 a, float4 b) {
  short8_t s = pack8s(a, b);
  return __builtin_bit_cast(bf16x8, s);
}
__device__ __forceinline__ bf16x8 ldfrag(const unsigned short* p) {   // 16B aligned
  short8_t s = *(const short8_t*)p;
  return __builtin_bit_cast(bf16x8, s);
}
__device__ __forceinline__ bf16x8 ldfrag8(const unsigned short* p) {  // 8B aligned
  union { ushort4 u4[2]; short8_t s8; } u;
  u.u4[0] = *(const ushort4*)p;
  u.u4[1] = *(const ushort4*)(p + 4);
  return __builtin_bit_cast(bf16x8, u.s8);
}
// swizzled 8-elem segment read: row r, seg (16B units), pitch 64, seg ^= r&7
__device__ __forceinline__ bf16x8 ldseg(const unsigned short* buf, int r, int seg) {
  return ldfrag(buf + r * 64 + ((seg ^ (r & 7)) << 3));
}
// async global->LDS, 16B/lane, LDS dest = base + lane*16
__device__ __forceinline__ void async16(const void* g, void* l) {
  __builtin_amdgcn_global_load_lds(
      (const __attribute__((address_space(1))) unsigned int*)(unsigned long long)(uintptr_t)g,
      (__attribute__((address_space(3))) unsigned int*)(unsigned int)(uintptr_t)l,
      16, 0, 0);
}
// stage 16 rows (8 rows per instr) of a row-major tile into swizzled pitch-64 LDS
__device__ __forceinline__ void stage16(const unsigned short* gb, size_t rstride,
                                        unsigned short* lb, int lane) {
  int srow = lane >> 3;
  int sseg = (lane & 7) ^ srow;
  async16(gb + (size_t)srow * rstride + sseg * 8, lb);
  async16(gb + (size_t)(srow + 8) * rstride + sseg * 8, lb + 512);
}
// stage this wave's 16 rows of emb ring slot sigma (64 global rows), clamped
__device__ __forceinline__ void stageE(const unsigned short* gb, int sigma,
                                       unsigned short* slot, int lane, int wv) {
  int srow = lane >> 3;
  int sseg = (lane & 7) ^ srow;
  int r0 = sigma * 64 + wv * 16 + srow;
  unsigned short* lb = slot + (wv * 16) * 64;
  async16(gb + (size_t)min(r0, R_LEN - 1) * D_DIM + sseg * 8, lb);
  async16(gb + (size_t)min(r0 + 8, R_LEN - 1) * D_DIM + sseg * 8, lb + 512);
}
// DPP 16-lane row reductions (VALU pipe, no LDS)
template<int N>
__device__ __forceinline__ float dpp_ror(float x) {
  int i = __builtin_bit_cast(int, x);
  int r = __builtin_amdgcn_update_dpp(i, i, 0x120 + N, 0xF, 0xF, false);
  return __builtin_bit_cast(float, r);
}
__device__ __forceinline__ float rmax16(float x) {
  x = fmaxf(x, dpp_ror<8>(x)); x = fmaxf(x, dpp_ror<4>(x));
  x = fmaxf(x, dpp_ror<2>(x)); x = fmaxf(x, dpp_ror<1>(x));
  return x;
}
__device__ __forceinline__ float rsum16(float x) {
  x += dpp_ror<8>(x); x += dpp_ror<4>(x);
  x += dpp_ror<2>(x); x += dpp_ror<1>(x);
  return x;
}

// ---------------- merged pre-pass: K->bf16, emb->bf16, V->V^T bf16 ----------------
extern "C" __global__ void prepass(const float* __restrict__ k, const float* __restrict__ v,
                                   const float* __restrict__ emb,
                                   unsigned short* __restrict__ kb,
                                   unsigned short* __restrict__ vtb,
                                   unsigned short* __restrict__ eb) {
  __shared__ unsigned short t[64 * PPITCH];
  const int bid = blockIdx.x;
  const int tid = threadIdx.x;
  if (bid < 4096) {                       // K
    size_t i = (size_t)bid * 256 + tid;
    const float* s = k + i * 8;
    float4 a = *(const float4*)s, b = *(const float4*)(s + 4);
    *(short8_t*)(kb + i * 8) = pack8s(a, b);
  } else if (bid < 4608) {                // emb
    size_t i = (size_t)(bid - 4096) * 256 + tid;
    if (i < 130944) {
      const float* s = emb + i * 8;
      float4 a = *(const float4*)s, b = *(const float4*)(s + 4);
      *(short8_t*)(eb + i * 8) = pack8s(a, b);
    }
  } else {                                // V transpose
    const int b2 = bid - 4608;
    const int bh = b2 >> 3;
    const int j0 = (b2 & 7) << 6;
    for (int idx = tid; idx < 1024; idx += 256) {
      int jl = idx >> 4, cg = (idx & 15) << 2;
      float4 a = *(const float4*)(v + (size_t)(j0 + jl) * BHD + bh * D_DIM + cg);
      ushort2 u0 = c2(a.x, a.y), u1 = c2(a.z, a.w);
      *(ushort4*)(t + jl * PPITCH + cg) = (ushort4){ u0.x, u0.y, u1.x, u1.y };
    }
    __syncthreads();
    for (int slot = tid; slot < 512; slot += 256) {
      int d = slot >> 3, jseg = slot & 7;
      union { unsigned short u[8]; short8_t s8; } r;
      #pragma unroll
      for (int jj = 0; jj < 8; ++jj) r.u[jj] = t[(jseg * 8 + jj) * PPITCH + d];
      *(short8_t*)(vtb + ((size_t)bh * D_DIM + d) * S_LEN + j0 + jseg * 8) = r.s8;
    }
  }
}

// ---------------- main attention kernel: dbuf pipeline, XCD-swizzled ----------------
extern "C" __global__ __launch_bounds__(256, 2)
void attn_relbias(const float* __restrict__ q, const unsigned short* __restrict__ kb,
                  const unsigned short* __restrict__ vtb,
                  const unsigned short* __restrict__ eb,
                  float* __restrict__ out)
{
  __shared__ unsigned short kbuf[2][4096];        // K_j tiles (swizzled pitch-64)
  __shared__ unsigned short vbuf[2][4096];        // V^T tiles
  __shared__ unsigned short ebuf[3][4096];        // emb ring: 3 slots x 64 rows
  __shared__ unsigned short ps[4][16 * PPITCH];   // per-wave P strip

  const int tid  = threadIdx.x;
  const int bh   = blockIdx.x & 255;              // same-bh blocks -> same XCD
  const int i0   = (blockIdx.x >> 8) << 6;
  const int h    = bh & (NH - 1);
  const int wv   = tid >> 6;
  const int lane = tid & 63;
  const int l15  = lane & 15;
  const int quad = lane >> 4;
  const int iloc0 = wv * 16 + quad * 4;
  const int elo   = 3 - wv;                       // wave's first bias e-block
  const int arow  = wv * 16 + l15;
  const int acol  = quad * 8;
  const int it0   = 7 - (i0 >> 6);                // sigma(t) = it0 + t

  const unsigned short* kgb  = kb  + (size_t)bh * D_DIM;            // + s*BHD
  const unsigned short* vgb  = vtb + (size_t)bh * (D_DIM * S_LEN);  // + d*512 + s
  const unsigned short* egb  = eb  + (size_t)h * (R_LEN * D_DIM);

  // ---- prologue: stage tile 0 (K,V) + emb slots it0, it0+1 ----
  stage16(kgb + (size_t)(wv * 16) * BHD, BHD, &kbuf[0][(wv * 16) * 64], lane);
  stage16(vgb + (size_t)(wv * 16) * S_LEN, S_LEN, &vbuf[0][(wv * 16) * 64], lane);
  stageE(egb, it0,     ebuf[it0 % 3],       lane, wv);
  stageE(egb, it0 + 1, ebuf[(it0 + 1) % 3], lane, wv);

  // ---- Q and K_i register fragments (plain global loads) ----
  bf16x8 qa0, qa1, ia0, ia1;
  {
    const float* gq = q + (size_t)(i0 + arow) * BHD + bh * D_DIM + acol;
    qa0 = pack8(*(const float4*)gq,        *(const float4*)(gq + 4));
    qa1 = pack8(*(const float4*)(gq + 32), *(const float4*)(gq + 36));
    const unsigned short* gi = kb + (size_t)(i0 + arow) * BHD + bh * D_DIM + acol;
    ia0 = ldfrag(gi);
    ia1 = ldfrag(gi + 32);
  }

  floatx4 oacc[4];
  #pragma unroll
  for (int c = 0; c < 4; ++c) oacc[c] = (floatx4){0.f, 0.f, 0.f, 0.f};
  float m_i[4] = { -1e30f, -1e30f, -1e30f, -1e30f };
  float l_i[4] = { 0.f, 0.f, 0.f, 0.f };

  __syncthreads();   // drain prologue staging

  #pragma unroll 2
  for (int t = 0; t < 8; ++t) {
    // ---- prefetch tile t+1 into the other buffers (drained at END barrier) ----
    if (t < 7) {
      const int j1 = t * 64 + 64;
      stage16(kgb + (size_t)(j1 + wv * 16) * BHD, BHD, &kbuf[(t + 1) & 1][(wv * 16) * 64], lane);
      stage16(vgb + (size_t)(wv * 16) * S_LEN + j1, S_LEN, &vbuf[(t + 1) & 1][(wv * 16) * 64], lane);
      stageE(egb, it0 + t + 2, ebuf[(it0 + t + 2) % 3], lane, wv);
    }
    const unsigned short* kc = kbuf[t & 1];
    const unsigned short* vc = vbuf[t & 1];

    // ---- bias MFMAs from emb ring ----
    floatx4 bacc[5];
    #pragma unroll
    for (int ei = 0; ei < 5; ++ei) {
      const int eblk = elo + ei;                         // 16-row block, never crosses slot
      const unsigned short* es = ebuf[(it0 + t + (eblk >> 2)) % 3];
      const int lr = (eblk * 16 + l15) & 63;
      floatx4 bz = (floatx4){0.f, 0.f, 0.f, 0.f};
      bz = __builtin_amdgcn_mfma_f32_16x16x32_bf16(ia0, ldseg(es, lr, quad),     bz, 0, 0, 0);
      bz = __builtin_amdgcn_mfma_f32_16x16x32_bf16(ia1, ldseg(es, lr, quad + 4), bz, 0, 0, 0);
      bacc[ei] = bz;
    }

    // ---- QK^T ----
    floatx4 qk[4];
    #pragma unroll
    for (int c = 0; c < 4; ++c) {
      floatx4 acc = (floatx4){0.f, 0.f, 0.f, 0.f};
      acc = __builtin_amdgcn_mfma_f32_16x16x32_bf16(qa0, ldseg(kc, c * 16 + l15, quad),     acc, 0, 0, 0);
      acc = __builtin_amdgcn_mfma_f32_16x16x32_bf16(qa1, ldseg(kc, c * 16 + l15, quad + 4), acc, 0, 0, 0);
      qk[c] = acc;
    }

    // ---- add bias via skew-shuffle ----
    float sc[4][4];
    #pragma unroll
    for (int r = 0; r < 4; ++r) {
      const int o  = 15 - 4 * quad - r;
      const int ls = (lane & 48) + ((l15 + o) & 15);
      const bool hi = (l15 + o) >= 16;
      #pragma unroll
      for (int c = 0; c < 4; ++c) {
        float blo = __shfl(bacc[c][r],     ls);
        float bhi = __shfl(bacc[c + 1][r], ls);
        sc[c][r] = (qk[c][r] + (hi ? bhi : blo)) * 0.125f;
      }
    }

    // ---- online softmax (DPP row reductions) ----
    float p[4][4];
    #pragma unroll
    for (int r = 0; r < 4; ++r) {
      float mx = fmaxf(fmaxf(sc[0][r], sc[1][r]), fmaxf(sc[2][r], sc[3][r]));
      mx = rmax16(mx);
      float mnew  = fmaxf(m_i[r], mx);
      float alpha = __expf(m_i[r] - mnew);
      float rs = 0.f;
      #pragma unroll
      for (int c = 0; c < 4; ++c) { p[c][r] = __expf(sc[c][r] - mnew); rs += p[c][r]; }
      rs = rsum16(rs);
      l_i[r] = l_i[r] * alpha + rs;
      m_i[r] = mnew;
      #pragma unroll
      for (int c = 0; c < 4; ++c) oacc[c][r] *= alpha;
    }

    // ---- P round-trip through wave-private LDS ----
    unsigned short* psw = ps[wv];
    #pragma unroll
    for (int r = 0; r < 4; ++r) {
      ushort2 u01 = c2(p[0][r], p[1][r]);
      ushort2 u23 = c2(p[2][r], p[3][r]);
      unsigned short* pr = psw + (quad * 4 + r) * PPITCH + l15;
      pr[0]  = u01.x; pr[16] = u01.y; pr[32] = u23.x; pr[48] = u23.y;
    }
    bf16x8 pa0 = ldfrag8(psw + l15 * PPITCH + acol);
    bf16x8 pa1 = ldfrag8(psw + l15 * PPITCH + acol + 32);

    // ---- PV ----
    #pragma unroll
    for (int c = 0; c < 4; ++c) {
      oacc[c] = __builtin_amdgcn_mfma_f32_16x16x32_bf16(pa0, ldseg(vc, c * 16 + l15, quad),     oacc[c], 0, 0, 0);
      oacc[c] = __builtin_amdgcn_mfma_f32_16x16x32_bf16(pa1, ldseg(vc, c * 16 + l15, quad + 4), oacc[c], 0, 0, 0);
    }

    __syncthreads();   // tile t reads done; prefetch t+1 drained (issued a full phase ago)
  }

  // ---- epilogue ----
  #pragma unroll
  for (int r = 0; r < 4; ++r) {
    float inv = 1.f / l_i[r];
    int row = i0 + iloc0 + r;
    #pragma unroll
    for (int c = 0; c < 4; ++c)
      out[(size_t)row * BHD + bh * D_DIM + c * 16 + l15] = oacc[c][r] * inv;
  }
}

// ---------------- fallback (used only if ws too small) ----------------
#define PITCH 72
extern "C" __global__ __launch_bounds__(256, 4)
void attn_fb(const float* __restrict__ q, const float* __restrict__ k,
             const float* __restrict__ v, const float* __restrict__ emb,
             float* __restrict__ out)
{
  __shared__ unsigned short kjs[64 * PITCH];
  __shared__ unsigned short vts[64 * PITCH];
  __shared__ unsigned short ps2[4][16 * PPITCH];

  const int tid  = threadIdx.x;
  const int bh   = blockIdx.x >> 3;
  const int i0   = (blockIdx.x & 7) << 6;
  const int h    = bh & (NH - 1);
  const int wv   = tid >> 6;
  const int lane = tid & 63;
  const int l15  = lane & 15;
  const int quad = lane >> 4;
  const int iloc0 = wv * 16 + quad * 4;
  const int elo   = 3 - wv;

  {
    const float* gq = q + (size_t)i0 * BHD + bh * D_DIM;
    const float* gk = k + (size_t)i0 * BHD + bh * D_DIM;
    for (int idx = tid; idx < 1024; idx += 256) {
      int row = idx >> 4, cg = (idx & 15) << 2;
      float4 a = *(const float4*)(gq + row * BHD + cg);
      float4 b = *(const float4*)(gk + row * BHD + cg);
      *(ushort4*)(vts + row * PITCH + cg) = (ushort4){ f2bf(a.x), f2bf(a.y), f2bf(a.z), f2bf(a.w) };
      *(ushort4*)(kjs + row * PITCH + cg) = (ushort4){ f2bf(b.x), f2bf(b.y), f2bf(b.z), f2bf(b.w) };
    }
  }
  __syncthreads();

  const int arow = wv * 16 + l15;
  const int acol = quad * 8;
  bf16x8 qa0 = ldfrag(vts + arow * PITCH + acol);
  bf16x8 qa1 = ldfrag(vts + arow * PITCH + acol + 32);
  bf16x8 ia0 = ldfrag(kjs + arow * PITCH + acol);
  bf16x8 ia1 = ldfrag(kjs + arow * PITCH + acol + 32);

  floatx4 oacc[4];
  #pragma unroll
  for (int c = 0; c < 4; ++c) oacc[c] = (floatx4){0.f, 0.f, 0.f, 0.f};
  float m_i[4] = { -1e30f, -1e30f, -1e30f, -1e30f };
  float l_i[4] = { 0.f, 0.f, 0.f, 0.f };

  for (int j0 = 0; j0 < S_LEN; j0 += 64) {
    __syncthreads();
    {
      const float* gk = k + (size_t)j0 * BHD + bh * D_DIM;
      for (int idx = tid; idx < 1024; idx += 256) {
        int row = idx >> 4, cg = (idx & 15) << 2;
        float4 b = *(const float4*)(gk + row * BHD + cg);
        *(ushort4*)(kjs + row * PITCH + cg) = (ushort4){ f2bf(b.x), f2bf(b.y), f2bf(b.z), f2bf(b.w) };
      }
    }
    {
      const float* gv = v + (size_t)j0 * BHD + bh * D_DIM;
      for (int idx = tid; idx < 1024; idx += 256) {
        int dg = idx & 15, jl = idx >> 4;
        float4 b = *(const float4*)(gv + jl * BHD + dg * 4);
        int d0 = dg * 4;
        vts[(d0 + 0) * PITCH + jl] = f2bf(b.x);
        vts[(d0 + 1) * PITCH + jl] = f2bf(b.y);
        vts[(d0 + 2) * PITCH + jl] = f2bf(b.z);
        vts[(d0 + 3) * PITCH + jl] = f2bf(b.w);
      }
    }
    floatx4 bacc[5];
    {
      const int rbase = j0 - i0 + 448;
      #pragma unroll
      for (int ei = 0; ei < 5; ++ei) {
        int rg = rbase + (elo + ei) * 16 + l15;
        rg = min(rg, R_LEN - 1);
        const float* ep = emb + ((size_t)h * R_LEN + rg) * D_DIM + acol;
        float4 e0 = *(const float4*)(ep);
        float4 e1 = *(const float4*)(ep + 4);
        float4 e2 = *(const float4*)(ep + 32);
        float4 e3 = *(const float4*)(ep + 36);
        floatx4 bz = (floatx4){0.f, 0.f, 0.f, 0.f};
        bz = __builtin_amdgcn_mfma_f32_16x16x32_bf16(ia0, pack8(e0, e1), bz, 0, 0, 0);
        bz = __builtin_amdgcn_mfma_f32_16x16x32_bf16(ia1, pack8(e2, e3), bz, 0, 0, 0);
        bacc[ei] = bz;
      }
    }
    __syncthreads();

    floatx4 qk[4];
    #pragma unroll
    for (int c = 0; c < 4; ++c) {
      bf16x8 kb0 = ldfrag(kjs + (c * 16 + l15) * PITCH + acol);
      bf16x8 kb1 = ldfrag(kjs + (c * 16 + l15) * PITCH + acol + 32);
      floatx4 acc = (floatx4){0.f, 0.f, 0.f, 0.f};
      acc = __builtin_amdgcn_mfma_f32_16x16x32_bf16(qa0, kb0, acc, 0, 0, 0);
      acc = __builtin_amdgcn_mfma_f32_16x16x32_bf16(qa1, kb1, acc, 0, 0, 0);
      qk[c] = acc;
    }
    float sc[4][4];
    #pragma unroll
    for (int r = 0; r < 4; ++r) {
      const int o  = 15 - 4 * quad - r;
      const int ls = (lane & 48) + ((l15 + o) & 15);
      const bool hi = (l15 + o) >= 16;
      #pragma unroll
      for (int c = 0; c < 4; ++c) {
        float blo = __shfl(bacc[c][r],     ls);
        float bhi = __shfl(bacc[c + 1][r], ls);
        sc[c][r] = (qk[c][r] + (hi ? bhi : blo)) * 0.125f;
      }
    }
    float p[4][4];
    #pragma unroll
    for (int r = 0; r < 4; ++r) {
      float mx = fmaxf(fmaxf(sc[0][r], sc[1][r]), fmaxf(sc[2][r], sc[3][r]));
      mx = rmax16(mx);
      float mnew  = fmaxf(m_i[r], mx);
      float alpha = __expf(m_i[r] - mnew);
      float rs = 0.f;
      #pragma unroll
      for (int c = 0; c < 4; ++c) { p[c][r] = __expf(sc[c][r] - mnew); rs += p[c][r]; }
      rs = rsum16(rs);
      l_i[r] = l_i[r] * alpha + rs;
      m_i[r] = mnew;
      #pragma unroll
      for (int c = 0; c < 4; ++c) oacc[c][r] *= alpha;
    }
    unsigned short* psw = ps2[wv];
    #pragma unroll
    for (int c = 0; c < 4; ++c) {
      #pragma unroll
      for (int r = 0; r < 4; ++r)
        psw[(quad * 4 + r) * PPITCH + c * 16 + l15] = f2bf(p[c][r]);
    }
    bf16x8 pa0 = ldfrag8(psw + l15 * PPITCH + acol);
    bf16x8 pa1 = ldfrag8(psw + l15 * PPITCH + acol + 32);
    #pragma unroll
    for (int c = 0; c < 4; ++c) {
      bf16x8 vb0 = ldfrag(vts + (c * 16 + l15) * PITCH + acol);
      bf16x8 vb1 = ldfrag(vts + (c * 16 + l15) * PITCH + acol + 32);
      oacc[c] = __builtin_amdgcn_mfma_f32_16x16x32_bf16(pa0, vb0, oacc[c], 0, 0, 0);
      oacc[c] = __builtin_amdgcn_mfma_f32_16x16x32_bf16(pa1, vb1, oacc[c], 0, 0, 0);
    }
  }
  #pragma unroll
  for (int r = 0; r < 4; ++r) {
    float inv = 1.f / l_i[r];
    int row = i0 + iloc0 + r;
    #pragma unroll
    for (int c = 0; c < 4; ++c)
      out[(size_t)row * BHD + bh * D_DIM + c * 16 + l15] = oacc[c][r] * inv;
  }
}

extern "C" void kernel_launch(void* const* d_in, const int* in_sizes, int n_in,
                              void* d_out, int out_size, void* d_ws, size_t ws_size,
                              hipStream_t stream) {
  const float* q   = (const float*)d_in[0];
  const float* k   = (const float*)d_in[1];
  const float* v   = (const float*)d_in[2];
  const float* emb = (const float*)d_in[3];
  float* out = (float*)d_out;

  const size_t kb_off  = 0;                       // 16 MiB
  const size_t vtb_off = (size_t)512 * 256 * 64 * 2;
  const size_t eb_off  = vtb_off * 2;             // + 16 MiB
  const size_t need    = eb_off + (size_t)NH * R_LEN * D_DIM * 2;

  if (ws_size >= need) {
    unsigned short* kbp  = (unsigned short*)((char*)d_ws + kb_off);
    unsigned short* vtbp = (unsigned short*)((char*)d_ws + vtb_off);
    unsigned short* ebp  = (unsigned short*)((char*)d_ws + eb_off);
    hipLaunchKernelGGL(prepass, dim3(6656), dim3(256), 0, stream, k, v, emb, kbp, vtbp, ebp);
    hipLaunchKernelGGL(attn_relbias, dim3(2048), dim3(256), 0, stream,
                       q, kbp, vtbp, ebp, out);
  } else {
    hipLaunchKernelGGL(attn_fb, dim3(2048), dim3(256), 0, stream, q, k, v, emb, out);
  }
}